// Round 5
// baseline (1090.223 us; speedup 1.0000x reference)
//
#include <hip/hip_runtime.h>
#include <cmath>

// x [B=4096][T=512][D=4], H=32, gates 4H=128. PyTorch gate order i,f,g,o.
constexpr int T  = 512;
constexpr int D  = 4;
constexpr int H  = 32;
constexpr int BT = 16;    // batch tile per wave (= MFMA N dim)

typedef short bf8 __attribute__((ext_vector_type(8)));  // 8 bf16 (4 VGPRs)
typedef float f4  __attribute__((ext_vector_type(4)));  // MFMA C/D

static __device__ __forceinline__ float sigm(float z) {
    return __builtin_amdgcn_rcpf(1.0f + __expf(-z));
}
static __device__ __forceinline__ float tanh_f(float z) {
    return fmaf(__builtin_amdgcn_rcpf(1.0f + __expf(-2.0f * z)), 2.0f, -1.0f);
}
// fp32 -> bf16 hi (truncate) + bf16 lo (residual). hi+lo captures ~16 mantissa bits.
static __device__ __forceinline__ void splitf(float v, short& hi, short& lo) {
    unsigned uv = __float_as_uint(v);
    hi = (short)(uv >> 16);
    float r = v - __uint_as_float(uv & 0xffff0000u);
    lo = (short)(__float_as_uint(r) >> 16);
}

// One wave per 16 batch elems. Per step, per layer: gates[128x16] =
// W[128x32] @ h[32x16] via 8 M-tiles of mfma_f32_16x16x32_bf16, 3 split
// products each. D layout: gate row = 16*tile + 4*q + r, batch col = nl
// (q=lane>>4, nl=lane&15). Activations are lane-local; h round-trips LDS
// to become the next B-fragment (B[k=8q+j][n=nl]). Single wave => no
// barriers, ds ordering via lgkmcnt.
__global__ __launch_bounds__(64, 1) void lstm_mfma(
    const float* __restrict__ x,
    const float* __restrict__ W_ih0, const float* __restrict__ W_hh0,
    const float* __restrict__ b_ih0, const float* __restrict__ b_hh0,
    const float* __restrict__ W_ih1, const float* __restrict__ W_hh1,
    const float* __restrict__ b_ih1, const float* __restrict__ b_hh1,
    const float* __restrict__ W_out, const float* __restrict__ b_out,
    float* __restrict__ out)
{
    __shared__ __align__(16) float hb0[BT * 36];        // h0, padded stride 36
    __shared__ __align__(16) float hb1[BT * 36];        // h1
    __shared__ __align__(16) short wx_lds[8][2][64 * 8]; // W_ih0 A-frags [tile][hi/lo][lane*8]

    const int lane = threadIdx.x;
    const int q    = lane >> 4;       // 0..3
    const int nl   = lane & 15;       // batch col within tile
    const int b0   = blockIdx.x * BT;

    // ---------------- weights -> register A-fragments (once) ----------------
    // A-frag for tile t8: lane holds W[16*t8 + nl][8q .. 8q+7] as 8 bf16.
    bf8 whh0h[8], whh0l[8], wih1h[8], wih1l[8], whh1h[8], whh1l[8];
    f4  bias0[8], bias1[8];
    #pragma unroll
    for (int t8 = 0; t8 < 8; ++t8) {
        const int row = 16 * t8 + nl;
        {
            const float* p = W_hh0 + row * H + 8 * q;
            #pragma unroll
            for (int j = 0; j < 8; ++j) { short a, b; splitf(p[j], a, b); whh0h[t8][j] = a; whh0l[t8][j] = b; }
        }
        {
            const float* p = W_ih1 + row * H + 8 * q;
            #pragma unroll
            for (int j = 0; j < 8; ++j) { short a, b; splitf(p[j], a, b); wih1h[t8][j] = a; wih1l[t8][j] = b; }
        }
        {
            const float* p = W_hh1 + row * H + 8 * q;
            #pragma unroll
            for (int j = 0; j < 8; ++j) { short a, b; splitf(p[j], a, b); whh1h[t8][j] = a; whh1l[t8][j] = b; }
        }
        // W_ih0 [128x4]: A-frag nonzero only for q==0, j<4 (k<4). Stash in LDS.
        {
            bf8 xh = {0,0,0,0,0,0,0,0}, xl = {0,0,0,0,0,0,0,0};
            if (q == 0) {
                const float* p = W_ih0 + row * D;
                #pragma unroll
                for (int j = 0; j < 4; ++j) { short a, b; splitf(p[j], a, b); xh[j] = a; xl[j] = b; }
            }
            *(bf8*)&wx_lds[t8][0][lane * 8] = xh;
            *(bf8*)&wx_lds[t8][1][lane * 8] = xl;
        }
        // bias fragments in C layout: element r -> gate row 16*t8 + 4q + r
        #pragma unroll
        for (int r = 0; r < 4; ++r) {
            bias0[t8][r] = b_ih0[16 * t8 + 4 * q + r] + b_hh0[16 * t8 + 4 * q + r];
            bias1[t8][r] = b_ih1[16 * t8 + 4 * q + r] + b_hh1[16 * t8 + 4 * q + r];
        }
    }
    float wo[2][4];
    #pragma unroll
    for (int p = 0; p < 2; ++p)
        #pragma unroll
        for (int r = 0; r < 4; ++r) wo[p][r] = W_out[16 * p + 4 * q + r];

    // ---------------- state ----------------
    bf8 h0hi = {0,0,0,0,0,0,0,0}, h0lo = {0,0,0,0,0,0,0,0};
    bf8 h1hi = {0,0,0,0,0,0,0,0}, h1lo = {0,0,0,0,0,0,0,0};
    float c0[2][4] = {{0,0,0,0},{0,0,0,0}};
    float c1[2][4] = {{0,0,0,0},{0,0,0,0}};
    float h1s[2][4] = {{0,0,0,0},{0,0,0,0}};

    const float4* xp = (const float4*)(x + (size_t)(b0 + nl) * (T * D));
    float4 xv = xp[0];

    #pragma unroll 1
    for (int t = 0; t < T; ++t) {
        // x B-fragment: B[k=j<4][n=nl] = x_t[j] (k>=4 zero; matching A cols are zero too)
        bf8 xhi = {0,0,0,0,0,0,0,0}, xlo = {0,0,0,0,0,0,0,0};
        { short a,b;
          splitf(xv.x, a, b); xhi[0]=a; xlo[0]=b;
          splitf(xv.y, a, b); xhi[1]=a; xlo[1]=b;
          splitf(xv.z, a, b); xhi[2]=a; xlo[2]=b;
          splitf(xv.w, a, b); xhi[3]=a; xlo[3]=b; }
        float4 xvn = xp[(t + 1 < T) ? (t + 1) : (T - 1)];   // prefetch

        // ---------------- layer 1 MFMAs ----------------
        f4 acc[8];
        #pragma unroll
        for (int t8 = 0; t8 < 8; ++t8) {
            bf8 axh = *(const bf8*)&wx_lds[t8][0][lane * 8];
            bf8 axl = *(const bf8*)&wx_lds[t8][1][lane * 8];
            f4 g = bias0[t8];
            g = __builtin_amdgcn_mfma_f32_16x16x32_bf16(whh0h[t8], h0hi, g, 0, 0, 0);
            g = __builtin_amdgcn_mfma_f32_16x16x32_bf16(whh0h[t8], h0lo, g, 0, 0, 0);
            g = __builtin_amdgcn_mfma_f32_16x16x32_bf16(whh0l[t8], h0hi, g, 0, 0, 0);
            g = __builtin_amdgcn_mfma_f32_16x16x32_bf16(axh,      xhi,  g, 0, 0, 0);
            g = __builtin_amdgcn_mfma_f32_16x16x32_bf16(axh,      xlo,  g, 0, 0, 0);
            g = __builtin_amdgcn_mfma_f32_16x16x32_bf16(axl,      xhi,  g, 0, 0, 0);
            acc[t8] = g;
        }
        // ---------------- layer 1 activations + h0 rebuild ----------------
        // lane holds, for batch nl: units u = 16p + 4q + r ; i=tile 0/1, f=2/3, g=4/5, o=6/7
        #pragma unroll
        for (int p = 0; p < 2; ++p) {
            float4 hw;
            float hr[4];
            #pragma unroll
            for (int r = 0; r < 4; ++r) {
                float iv = sigm(acc[0 + p][r]);
                float fv = sigm(acc[2 + p][r]);
                float gv = tanh_f(acc[4 + p][r]);
                float ov = sigm(acc[6 + p][r]);
                c0[p][r] = fmaf(fv, c0[p][r], iv * gv);
                hr[r] = ov * tanh_f(c0[p][r]);
            }
            hw.x = hr[0]; hw.y = hr[1]; hw.z = hr[2]; hw.w = hr[3];
            *(float4*)&hb0[nl * 36 + 16 * p + 4 * q] = hw;
        }
        {   // read back as B-frag: lane needs h0[8q..8q+7] of batch nl
            float4 ha = *(const float4*)&hb0[nl * 36 + 8 * q];
            float4 hb = *(const float4*)&hb0[nl * 36 + 8 * q + 4];
            short a, b;
            splitf(ha.x, a, b); h0hi[0]=a; h0lo[0]=b;
            splitf(ha.y, a, b); h0hi[1]=a; h0lo[1]=b;
            splitf(ha.z, a, b); h0hi[2]=a; h0lo[2]=b;
            splitf(ha.w, a, b); h0hi[3]=a; h0lo[3]=b;
            splitf(hb.x, a, b); h0hi[4]=a; h0lo[4]=b;
            splitf(hb.y, a, b); h0hi[5]=a; h0lo[5]=b;
            splitf(hb.z, a, b); h0hi[6]=a; h0lo[6]=b;
            splitf(hb.w, a, b); h0hi[7]=a; h0lo[7]=b;
        }

        // ---------------- layer 2 MFMAs ----------------
        #pragma unroll
        for (int t8 = 0; t8 < 8; ++t8) {
            f4 g = bias1[t8];
            g = __builtin_amdgcn_mfma_f32_16x16x32_bf16(wih1h[t8], h0hi, g, 0, 0, 0);
            g = __builtin_amdgcn_mfma_f32_16x16x32_bf16(wih1h[t8], h0lo, g, 0, 0, 0);
            g = __builtin_amdgcn_mfma_f32_16x16x32_bf16(wih1l[t8], h0hi, g, 0, 0, 0);
            g = __builtin_amdgcn_mfma_f32_16x16x32_bf16(whh1h[t8], h1hi, g, 0, 0, 0);
            g = __builtin_amdgcn_mfma_f32_16x16x32_bf16(whh1h[t8], h1lo, g, 0, 0, 0);
            g = __builtin_amdgcn_mfma_f32_16x16x32_bf16(whh1l[t8], h1hi, g, 0, 0, 0);
            acc[t8] = g;
        }
        // ---------------- layer 2 activations + h1 rebuild ----------------
        #pragma unroll
        for (int p = 0; p < 2; ++p) {
            float4 hw;
            float hr[4];
            #pragma unroll
            for (int r = 0; r < 4; ++r) {
                float iv = sigm(acc[0 + p][r]);
                float fv = sigm(acc[2 + p][r]);
                float gv = tanh_f(acc[4 + p][r]);
                float ov = sigm(acc[6 + p][r]);
                c1[p][r] = fmaf(fv, c1[p][r], iv * gv);
                hr[r] = ov * tanh_f(c1[p][r]);
                h1s[p][r] = hr[r];
            }
            hw.x = hr[0]; hw.y = hr[1]; hw.z = hr[2]; hw.w = hr[3];
            *(float4*)&hb1[nl * 36 + 16 * p + 4 * q] = hw;
        }
        {
            float4 ha = *(const float4*)&hb1[nl * 36 + 8 * q];
            float4 hb = *(const float4*)&hb1[nl * 36 + 8 * q + 4];
            short a, b;
            splitf(ha.x, a, b); h1hi[0]=a; h1lo[0]=b;
            splitf(ha.y, a, b); h1hi[1]=a; h1lo[1]=b;
            splitf(ha.z, a, b); h1hi[2]=a; h1lo[2]=b;
            splitf(ha.w, a, b); h1hi[3]=a; h1lo[3]=b;
            splitf(hb.x, a, b); h1hi[4]=a; h1lo[4]=b;
            splitf(hb.y, a, b); h1hi[5]=a; h1lo[5]=b;
            splitf(hb.z, a, b); h1hi[6]=a; h1lo[6]=b;
            splitf(hb.w, a, b); h1hi[7]=a; h1lo[7]=b;
        }

        xv = xvn;
    }

    // ---------------- output head ----------------
    // out[b0+nl] = b_out + sum_u W_out[u]*h1[u];  lane holds units 16p+4q+r.
    float s = 0.0f;
    #pragma unroll
    for (int p = 0; p < 2; ++p)
        #pragma unroll
        for (int r = 0; r < 4; ++r) s = fmaf(wo[p][r], h1s[p][r], s);
    s += __shfl_xor(s, 16);   // combine q bit 0
    s += __shfl_xor(s, 32);   // combine q bit 1
    if (lane < BT) out[b0 + lane] = s + b_out[0];
}

extern "C" void kernel_launch(void* const* d_in, const int* in_sizes, int n_in,
                              void* d_out, int out_size, void* d_ws, size_t ws_size,
                              hipStream_t stream) {
    const float* x     = (const float*)d_in[0];
    const float* W_ih0 = (const float*)d_in[1];
    const float* W_hh0 = (const float*)d_in[2];
    const float* b_ih0 = (const float*)d_in[3];
    const float* b_hh0 = (const float*)d_in[4];
    const float* W_ih1 = (const float*)d_in[5];
    const float* W_hh1 = (const float*)d_in[6];
    const float* b_ih1 = (const float*)d_in[7];
    const float* b_hh1 = (const float*)d_in[8];
    const float* W_out = (const float*)d_in[9];
    const float* b_out = (const float*)d_in[10];
    float* out = (float*)d_out;

    const int B = out_size;          // 4096
    lstm_mfma<<<B / BT, 64, 0, stream>>>(x, W_ih0, W_hh0, b_ih0, b_hh0,
                                         W_ih1, W_hh1, b_ih1, b_hh1,
                                         W_out, b_out, out);
}

// Round 6
// 504.845 us; speedup vs baseline: 2.1595x; 2.1595x over previous
//
#include <hip/hip_runtime.h>
#include <cmath>

// x [B=4096][T=512][D=4], H=32, gates 4H=128 (PyTorch order i,f,g,o).
constexpr int T  = 512;
constexpr int D  = 4;
constexpr int H  = 32;
constexpr int BT = 16;    // batch tile per block (= MFMA N dim)

typedef short bf8 __attribute__((ext_vector_type(8)));  // 8 bf16 (4 VGPRs)
typedef short s4v __attribute__((ext_vector_type(4)));  // 4 bf16 (8B)
typedef float f4  __attribute__((ext_vector_type(4)));  // MFMA C/D

static __device__ __forceinline__ float sigm(float z) {
    return __builtin_amdgcn_rcpf(1.0f + __expf(-z));
}
static __device__ __forceinline__ float tanh_f(float z) {
    return fmaf(__builtin_amdgcn_rcpf(1.0f + __expf(-2.0f * z)), 2.0f, -1.0f);
}
// fp32 -> bf16 hi (truncate) + bf16 lo (residual): hi+lo ~ 16 mantissa bits
static __device__ __forceinline__ void splitf(float v, short& hi, short& lo) {
    unsigned uv = __float_as_uint(v);
    hi = (short)(uv >> 16);
    float r = v - __uint_as_float(uv & 0xffff0000u);
    lo = (short)(__float_as_uint(r) >> 16);
}

// Block = 16 batch elems, 4 waves. Wave w owns gate rows [32w, 32w+32)
// (= gate type w: 0=i,1=f,2=g,3=o) as 2 MFMA M-tiles, for BOTH layers.
// Iteration i (pipeline skew): phase A computes raw gates of L1 step i and
// L2 step i-1 — both consume h0(i-1), one shared B-fragment. Phase B:
// waves 0,1 do the L1 state update (units 0-31 x 16 batch, 4/lane),
// waves 2,3 do L2. h is stored in LDS PRE-SPLIT as bf16 hi/lo so phase-A
// consumers load fragments with ds_read_b128, no per-consumer splitting.
// 2 barriers per step.
__global__ __launch_bounds__(256, 1) void lstm_mfma4(
    const float* __restrict__ x,
    const float* __restrict__ W_ih0, const float* __restrict__ W_hh0,
    const float* __restrict__ b_ih0, const float* __restrict__ b_hh0,
    const float* __restrict__ W_ih1, const float* __restrict__ W_hh1,
    const float* __restrict__ b_ih1, const float* __restrict__ b_hh1,
    const float* __restrict__ W_out, const float* __restrict__ b_out,
    float* __restrict__ out)
{
    __shared__ __align__(16) float g0[BT][132];     // raw L1 gates [batch][row], pad 132
    __shared__ __align__(16) float g1[BT][132];     // raw L2 gates
    __shared__ __align__(16) short h0hi[BT][48];    // h0 split-bf16, pad 48 (96B rows)
    __shared__ __align__(16) short h0lo[BT][48];
    __shared__ __align__(16) short h1hi[BT][48];
    __shared__ __align__(16) short h1lo[BT][48];
    __shared__ __align__(16) float h1f[BT][36];     // final h1 in fp32 for the head

    const int tid  = threadIdx.x;
    const int w    = tid >> 6;        // wave = gate type
    const int lane = tid & 63;
    const int q    = lane >> 4;       // quad
    const int nl   = lane & 15;       // batch col
    const int b0   = blockIdx.x * BT;

    // zero the h LDS (h0(-1)=h1(-2)=h1(-1)=0)
    for (int idx = tid; idx < BT * 48; idx += 256) {
        (&h0hi[0][0])[idx] = 0; (&h0lo[0][0])[idx] = 0;
        (&h1hi[0][0])[idx] = 0; (&h1lo[0][0])[idx] = 0;
    }

    // ---- weights: wave w, tile p -> A-frag rows W[32w+16p+nl][8q+j] ----
    bf8 whh0h[2], whh0l[2], wx0h[2], wx0l[2], wih1h[2], wih1l[2], whh1h[2], whh1l[2];
    f4  bias0[2], bias1[2];
    #pragma unroll
    for (int p = 0; p < 2; ++p) {
        const int row = 32 * w + 16 * p + nl;
        #pragma unroll
        for (int j = 0; j < 8; ++j) {
            short a, b;
            splitf(W_hh0[row * H + 8 * q + j], a, b); whh0h[p][j] = a; whh0l[p][j] = b;
            splitf(W_ih1[row * H + 8 * q + j], a, b); wih1h[p][j] = a; wih1l[p][j] = b;
            splitf(W_hh1[row * H + 8 * q + j], a, b); whh1h[p][j] = a; whh1l[p][j] = b;
            float xw = (q == 0 && j < 4) ? W_ih0[row * D + j] : 0.0f;  // K-pad
            splitf(xw, a, b); wx0h[p][j] = a; wx0l[p][j] = b;
        }
        #pragma unroll
        for (int rr = 0; rr < 4; ++rr) {
            const int gr = 32 * w + 16 * p + 4 * q + rr;   // C/D row of this reg
            bias0[p][rr] = b_ih0[gr] + b_hh0[gr];
            bias1[p][rr] = b_ih1[gr] + b_hh1[gr];
        }
    }

    const float4* xp = (const float4*)(x + (size_t)(b0 + nl) * (T * D));
    float4 xcur = xp[0];

    float c0r[4] = {0, 0, 0, 0};            // L1 cell state (waves 0,1)
    float c1r[4] = {0, 0, 0, 0};            // L2 cell state (waves 2,3)
    const int ug = ((w & 1) << 2) | q;      // unit-group 0..7 owned in phase B

    __syncthreads();

    #pragma unroll 1
    for (int i = 0; i <= T; ++i) {
        // ================= phase A: MFMA raw gates =================
        bf8 h0h = *(const bf8*)&h0hi[nl][8 * q];    // h0(i-1) fragment
        bf8 h0l = *(const bf8*)&h0lo[nl][8 * q];
        bf8 h1h = *(const bf8*)&h1hi[nl][8 * q];    // h1(i-2) fragment
        bf8 h1l = *(const bf8*)&h1lo[nl][8 * q];
        bf8 xh = {0,0,0,0,0,0,0,0}, xl = {0,0,0,0,0,0,0,0};
        {   // B-frag k<4 = x(i); k>=4 multiplied by zero A cols
            short a, b;
            splitf(xcur.x, a, b); xh[0] = a; xl[0] = b;
            splitf(xcur.y, a, b); xh[1] = a; xl[1] = b;
            splitf(xcur.z, a, b); xh[2] = a; xl[2] = b;
            splitf(xcur.w, a, b); xh[3] = a; xl[3] = b;
        }
        xcur = xp[(i + 1 < T) ? (i + 1) : (T - 1)];  // prefetch next x

        #pragma unroll
        for (int p = 0; p < 2; ++p) {
            f4 a = bias0[p];   // L1(i) = W_hh0 h0 + W_ih0 x + b
            a = __builtin_amdgcn_mfma_f32_16x16x32_bf16(whh0h[p], h0h, a, 0, 0, 0);
            a = __builtin_amdgcn_mfma_f32_16x16x32_bf16(whh0h[p], h0l, a, 0, 0, 0);
            a = __builtin_amdgcn_mfma_f32_16x16x32_bf16(whh0l[p], h0h, a, 0, 0, 0);
            a = __builtin_amdgcn_mfma_f32_16x16x32_bf16(wx0h[p],  xh,  a, 0, 0, 0);
            a = __builtin_amdgcn_mfma_f32_16x16x32_bf16(wx0h[p],  xl,  a, 0, 0, 0);
            a = __builtin_amdgcn_mfma_f32_16x16x32_bf16(wx0l[p],  xh,  a, 0, 0, 0);
            *(f4*)&g0[nl][32 * w + 16 * p + 4 * q] = a;

            f4 b = bias1[p];   // L2(i-1) = W_ih1 h0 + W_hh1 h1 + b
            b = __builtin_amdgcn_mfma_f32_16x16x32_bf16(wih1h[p], h0h, b, 0, 0, 0);
            b = __builtin_amdgcn_mfma_f32_16x16x32_bf16(wih1h[p], h0l, b, 0, 0, 0);
            b = __builtin_amdgcn_mfma_f32_16x16x32_bf16(wih1l[p], h0h, b, 0, 0, 0);
            b = __builtin_amdgcn_mfma_f32_16x16x32_bf16(whh1h[p], h1h, b, 0, 0, 0);
            b = __builtin_amdgcn_mfma_f32_16x16x32_bf16(whh1h[p], h1l, b, 0, 0, 0);
            b = __builtin_amdgcn_mfma_f32_16x16x32_bf16(whh1l[p], h1h, b, 0, 0, 0);
            *(f4*)&g1[nl][32 * w + 16 * p + 4 * q] = b;
        }
        __syncthreads();

        // ================= phase B: state updates =================
        if (w < 2) {
            if (i < T) {   // L1 step i: units 4ug..4ug+3, batch nl
                f4 gi = *(const f4*)&g0[nl][ 0 + 4 * ug];
                f4 gf = *(const f4*)&g0[nl][32 + 4 * ug];
                f4 gg = *(const f4*)&g0[nl][64 + 4 * ug];
                f4 go = *(const f4*)&g0[nl][96 + 4 * ug];
                s4v hh, hl;
                #pragma unroll
                for (int r = 0; r < 4; ++r) {
                    float iv = sigm(gi[r]), fv = sigm(gf[r]);
                    float gv = tanh_f(gg[r]), ov = sigm(go[r]);
                    c0r[r] = fmaf(fv, c0r[r], iv * gv);
                    float hv = ov * tanh_f(c0r[r]);
                    short a, b; splitf(hv, a, b); hh[r] = a; hl[r] = b;
                }
                *(s4v*)&h0hi[nl][4 * ug] = hh;
                *(s4v*)&h0lo[nl][4 * ug] = hl;
            }
        } else {
            if (i >= 1) {  // L2 step i-1
                f4 gi = *(const f4*)&g1[nl][ 0 + 4 * ug];
                f4 gf = *(const f4*)&g1[nl][32 + 4 * ug];
                f4 gg = *(const f4*)&g1[nl][64 + 4 * ug];
                f4 go = *(const f4*)&g1[nl][96 + 4 * ug];
                s4v hh, hl;
                float hvr[4];
                #pragma unroll
                for (int r = 0; r < 4; ++r) {
                    float iv = sigm(gi[r]), fv = sigm(gf[r]);
                    float gv = tanh_f(gg[r]), ov = sigm(go[r]);
                    c1r[r] = fmaf(fv, c1r[r], iv * gv);
                    hvr[r] = ov * tanh_f(c1r[r]);
                    short a, b; splitf(hvr[r], a, b); hh[r] = a; hl[r] = b;
                }
                *(s4v*)&h1hi[nl][4 * ug] = hh;
                *(s4v*)&h1lo[nl][4 * ug] = hl;
                if (i == T) {   // h1(T-1) in full fp32 for the output head
                    float4 hw; hw.x = hvr[0]; hw.y = hvr[1]; hw.z = hvr[2]; hw.w = hvr[3];
                    *(float4*)&h1f[nl][4 * ug] = hw;
                }
            }
        }
        __syncthreads();
    }

    // ---- output head: out[b0+n] = b_out + W_out . h1(T-1) ----
    if (tid < BT) {
        float acc = b_out[0];
        #pragma unroll
        for (int u = 0; u < H; ++u) acc = fmaf(W_out[u], h1f[tid][u], acc);
        out[b0 + tid] = acc;
    }
}

extern "C" void kernel_launch(void* const* d_in, const int* in_sizes, int n_in,
                              void* d_out, int out_size, void* d_ws, size_t ws_size,
                              hipStream_t stream) {
    const float* x     = (const float*)d_in[0];
    const float* W_ih0 = (const float*)d_in[1];
    const float* W_hh0 = (const float*)d_in[2];
    const float* b_ih0 = (const float*)d_in[3];
    const float* b_hh0 = (const float*)d_in[4];
    const float* W_ih1 = (const float*)d_in[5];
    const float* W_hh1 = (const float*)d_in[6];
    const float* b_ih1 = (const float*)d_in[7];
    const float* b_hh1 = (const float*)d_in[8];
    const float* W_out = (const float*)d_in[9];
    const float* b_out = (const float*)d_in[10];
    float* out = (float*)d_out;

    const int B = out_size;          // 4096
    lstm_mfma4<<<B / BT, 256, 0, stream>>>(x, W_ih0, W_hh0, b_ih0, b_hh0,
                                           W_ih1, W_hh1, b_ih1, b_hh1,
                                           W_out, b_out, out);
}

// Round 7
// 482.362 us; speedup vs baseline: 2.2602x; 1.0466x over previous
//
#include <hip/hip_runtime.h>
#include <cmath>

// x [B=4096][T=512][D=4], H=32, gates 4H=128 (PyTorch order i,f,g,o).
constexpr int T    = 512;
constexpr int D    = 4;
constexpr int H    = 32;
constexpr int BT   = 8;      // batch per block (MFMA N dim half-used, buys 2 blocks/CU)
constexpr int BTOT = 4096;

typedef short bf8 __attribute__((ext_vector_type(8)));  // 8 bf16 (4 VGPRs)
typedef short s2v __attribute__((ext_vector_type(2)));  // 2 bf16 (4B)
typedef float f4  __attribute__((ext_vector_type(4)));  // MFMA C/D
typedef float f2  __attribute__((ext_vector_type(2)));

static __device__ __forceinline__ float sigm(float z) {
    return __builtin_amdgcn_rcpf(1.0f + __expf(-z));
}
static __device__ __forceinline__ float tanh_f(float z) {
    return fmaf(__builtin_amdgcn_rcpf(1.0f + __expf(-2.0f * z)), 2.0f, -1.0f);
}
// fp32 -> bf16 hi (truncate) + bf16 lo (residual): hi+lo ~ 16 mantissa bits
static __device__ __forceinline__ void splitf(float v, short& hi, short& lo) {
    unsigned uv = __float_as_uint(v);
    hi = (short)(uv >> 16);
    float r = v - __uint_as_float(uv & 0xffff0000u);
    lo = (short)(__float_as_uint(r) >> 16);
}

// Block = 8 batch elems, 4 waves; grid 512 = 2 blocks/CU (independent
// barriers -> cross-block phase overlap on every SIMD). Wave w owns gate
// rows [32w,32w+32) of BOTH layers (2 M-tiles); MFMA N-cols 8..15 carry
// zeros/garbage, never read. Phase B: waves 0,1 -> L1, waves 2,3 -> L2,
// ALL 128 lanes per layer active with 2 units each (halves transcendental
// issue vs 4-units-on-half-lanes). h stored pre-split bf16 hi/lo, row
// stride 56 shorts (odd float4 stride -> no bank-quad aliasing).
__global__ __launch_bounds__(256, 2) void lstm_mfma8(
    const float* __restrict__ x,
    const float* __restrict__ W_ih0, const float* __restrict__ W_hh0,
    const float* __restrict__ b_ih0, const float* __restrict__ b_hh0,
    const float* __restrict__ W_ih1, const float* __restrict__ W_hh1,
    const float* __restrict__ b_ih1, const float* __restrict__ b_hh1,
    const float* __restrict__ W_out, const float* __restrict__ b_out,
    float* __restrict__ out)
{
    __shared__ __align__(16) float g0[16][132];     // raw L1 gates [batchcol][row]
    __shared__ __align__(16) float g1[16][132];     // raw L2 gates
    __shared__ __align__(16) short h0hi[16][56];    // h0 split-bf16 (rows 8-15 stay 0)
    __shared__ __align__(16) short h0lo[16][56];
    __shared__ __align__(16) short h1hi[16][56];
    __shared__ __align__(16) short h1lo[16][56];
    __shared__ __align__(16) float h1f[BT][36];     // final h1 fp32 for the head

    const int tid  = threadIdx.x;
    const int w    = tid >> 6;        // wave = gate type (phase A)
    const int lane = tid & 63;
    const int q    = lane >> 4;       // quad
    const int nl   = lane & 15;       // MFMA batch col
    const int b0   = blockIdx.x * BT;

    // zero h LDS (incl. cols 8-15 which stay zero forever)
    for (int idx = tid; idx < 16 * 56; idx += 256) {
        (&h0hi[0][0])[idx] = 0; (&h0lo[0][0])[idx] = 0;
        (&h1hi[0][0])[idx] = 0; (&h1lo[0][0])[idx] = 0;
    }

    // ---- weights: wave w, tile p -> A-frag rows W[32w+16p+nl][8q+j] ----
    bf8 whh0h[2], whh0l[2], wx0h[2], wx0l[2], wih1h[2], wih1l[2], whh1h[2], whh1l[2];
    f4  bias0[2], bias1[2];
    #pragma unroll
    for (int p = 0; p < 2; ++p) {
        const int row = 32 * w + 16 * p + nl;
        #pragma unroll
        for (int j = 0; j < 8; ++j) {
            short a, b;
            splitf(W_hh0[row * H + 8 * q + j], a, b); whh0h[p][j] = a; whh0l[p][j] = b;
            splitf(W_ih1[row * H + 8 * q + j], a, b); wih1h[p][j] = a; wih1l[p][j] = b;
            splitf(W_hh1[row * H + 8 * q + j], a, b); whh1h[p][j] = a; whh1l[p][j] = b;
            float xw = (q == 0 && j < 4) ? W_ih0[row * D + j] : 0.0f;  // K-pad
            splitf(xw, a, b); wx0h[p][j] = a; wx0l[p][j] = b;
        }
        #pragma unroll
        for (int rr = 0; rr < 4; ++rr) {
            const int gr = 32 * w + 16 * p + 4 * q + rr;
            bias0[p][rr] = b_ih0[gr] + b_hh0[gr];
            bias1[p][rr] = b_ih1[gr] + b_hh1[gr];
        }
    }

    // x stream for MFMA col nl (clamped: cols >= BT produce unused garbage)
    const int bx = (b0 + nl < BTOT) ? (b0 + nl) : (BTOT - 1);
    const float4* xp = (const float4*)(x + (size_t)bx * (T * D));
    float4 xcur = xp[0];

    // ---- phase-B mapping: all 128 lanes per layer, 2 units each ----
    const int layer = w >> 1;                   // waves 0,1 -> L1; 2,3 -> L2
    const int idxB  = ((w & 1) << 6) | lane;    // 0..127 within layer
    const int n8    = idxB & 7;                 // batch 0..7
    const int j2    = idxB >> 3;                // unit pair 0..15 -> units 2j2,2j2+1
    float cst[2] = {0.0f, 0.0f};                // cell state for the 2 owned units

    __syncthreads();

    #pragma unroll 1
    for (int i = 0; i <= T; ++i) {
        // ================= phase A: MFMA raw gates =================
        bf8 h0h = *(const bf8*)&h0hi[nl][8 * q];    // h0(i-1)
        bf8 h0l = *(const bf8*)&h0lo[nl][8 * q];
        bf8 h1h = *(const bf8*)&h1hi[nl][8 * q];    // h1(i-2)
        bf8 h1l = *(const bf8*)&h1lo[nl][8 * q];
        bf8 xh = {0,0,0,0,0,0,0,0}, xl = {0,0,0,0,0,0,0,0};
        {
            short a, b;
            splitf(xcur.x, a, b); xh[0] = a; xl[0] = b;
            splitf(xcur.y, a, b); xh[1] = a; xl[1] = b;
            splitf(xcur.z, a, b); xh[2] = a; xl[2] = b;
            splitf(xcur.w, a, b); xh[3] = a; xl[3] = b;
        }
        xcur = xp[(i + 1 < T) ? (i + 1) : (T - 1)];  // prefetch

        #pragma unroll
        for (int p = 0; p < 2; ++p) {
            f4 a = bias0[p];   // L1(i) = W_hh0 h0 + W_ih0 x + b
            a = __builtin_amdgcn_mfma_f32_16x16x32_bf16(whh0h[p], h0h, a, 0, 0, 0);
            a = __builtin_amdgcn_mfma_f32_16x16x32_bf16(whh0h[p], h0l, a, 0, 0, 0);
            a = __builtin_amdgcn_mfma_f32_16x16x32_bf16(whh0l[p], h0h, a, 0, 0, 0);
            a = __builtin_amdgcn_mfma_f32_16x16x32_bf16(wx0h[p],  xh,  a, 0, 0, 0);
            a = __builtin_amdgcn_mfma_f32_16x16x32_bf16(wx0h[p],  xl,  a, 0, 0, 0);
            a = __builtin_amdgcn_mfma_f32_16x16x32_bf16(wx0l[p],  xh,  a, 0, 0, 0);
            *(f4*)&g0[nl][32 * w + 16 * p + 4 * q] = a;

            f4 b = bias1[p];   // L2(i-1) = W_ih1 h0 + W_hh1 h1 + b
            b = __builtin_amdgcn_mfma_f32_16x16x32_bf16(wih1h[p], h0h, b, 0, 0, 0);
            b = __builtin_amdgcn_mfma_f32_16x16x32_bf16(wih1h[p], h0l, b, 0, 0, 0);
            b = __builtin_amdgcn_mfma_f32_16x16x32_bf16(wih1l[p], h0h, b, 0, 0, 0);
            b = __builtin_amdgcn_mfma_f32_16x16x32_bf16(whh1h[p], h1h, b, 0, 0, 0);
            b = __builtin_amdgcn_mfma_f32_16x16x32_bf16(whh1h[p], h1l, b, 0, 0, 0);
            b = __builtin_amdgcn_mfma_f32_16x16x32_bf16(whh1l[p], h1h, b, 0, 0, 0);
            *(f4*)&g1[nl][32 * w + 16 * p + 4 * q] = b;
        }
        __syncthreads();

        // ================= phase B: state updates (2 units/lane) =================
        if (layer == 0) {
            if (i < T) {
                f2 gi = *(const f2*)&g0[n8][ 0 + 2 * j2];
                f2 gf = *(const f2*)&g0[n8][32 + 2 * j2];
                f2 gg = *(const f2*)&g0[n8][64 + 2 * j2];
                f2 go = *(const f2*)&g0[n8][96 + 2 * j2];
                s2v hh, hl;
                #pragma unroll
                for (int r = 0; r < 2; ++r) {
                    float iv = sigm(gi[r]), fv = sigm(gf[r]);
                    float gv = tanh_f(gg[r]), ov = sigm(go[r]);
                    cst[r] = fmaf(fv, cst[r], iv * gv);
                    float hv = ov * tanh_f(cst[r]);
                    short a, b; splitf(hv, a, b); hh[r] = a; hl[r] = b;
                }
                *(s2v*)&h0hi[n8][2 * j2] = hh;
                *(s2v*)&h0lo[n8][2 * j2] = hl;
            }
        } else {
            if (i >= 1) {
                f2 gi = *(const f2*)&g1[n8][ 0 + 2 * j2];
                f2 gf = *(const f2*)&g1[n8][32 + 2 * j2];
                f2 gg = *(const f2*)&g1[n8][64 + 2 * j2];
                f2 go = *(const f2*)&g1[n8][96 + 2 * j2];
                s2v hh, hl;
                f2 hv2;
                #pragma unroll
                for (int r = 0; r < 2; ++r) {
                    float iv = sigm(gi[r]), fv = sigm(gf[r]);
                    float gv = tanh_f(gg[r]), ov = sigm(go[r]);
                    cst[r] = fmaf(fv, cst[r], iv * gv);
                    float hv = ov * tanh_f(cst[r]);
                    hv2[r] = hv;
                    short a, b; splitf(hv, a, b); hh[r] = a; hl[r] = b;
                }
                *(s2v*)&h1hi[n8][2 * j2] = hh;
                *(s2v*)&h1lo[n8][2 * j2] = hl;
                if (i == T) *(f2*)&h1f[n8][2 * j2] = hv2;   // h1(T-1) for the head
            }
        }
        __syncthreads();
    }

    // ---- output head: out[b0+n] = b_out + W_out . h1(T-1) ----
    if (tid < BT) {
        float acc = b_out[0];
        #pragma unroll
        for (int u = 0; u < H; ++u) acc = fmaf(W_out[u], h1f[tid][u], acc);
        out[b0 + tid] = acc;
    }
}

extern "C" void kernel_launch(void* const* d_in, const int* in_sizes, int n_in,
                              void* d_out, int out_size, void* d_ws, size_t ws_size,
                              hipStream_t stream) {
    const float* x     = (const float*)d_in[0];
    const float* W_ih0 = (const float*)d_in[1];
    const float* W_hh0 = (const float*)d_in[2];
    const float* b_ih0 = (const float*)d_in[3];
    const float* b_hh0 = (const float*)d_in[4];
    const float* W_ih1 = (const float*)d_in[5];
    const float* W_hh1 = (const float*)d_in[6];
    const float* b_ih1 = (const float*)d_in[7];
    const float* b_hh1 = (const float*)d_in[8];
    const float* W_out = (const float*)d_in[9];
    const float* b_out = (const float*)d_in[10];
    float* out = (float*)d_out;

    const int B = out_size;          // 4096
    lstm_mfma8<<<B / BT, 256, 0, stream>>>(x, W_ih0, W_hh0, b_ih0, b_hh0,
                                           W_ih1, W_hh1, b_ih1, b_hh1,
                                           W_out, b_out, out);
}